// Round 19
// baseline (40.720 us; speedup 1.0000x reference)
//
#include <hip/hip_runtime.h>
#include <math.h>

#define B_N 4096
#define C_N 100
#define D_N 384
#define EPSF 1e-12f
#define CT 5           // classes per tile
#define NT 20          // class tiles
#define NK (D_N / 16)  // 24 k-steps of 16 dims
#define KW (NK / 4)    // 6 k-steps per wave
#define RT 64          // rows per block-sub (4 rows per thread)
#define NRT (B_N / RT) // 64 input rowtiles; rowtiles 64,65 are center rows
#define SUBS 2         // rowtiles per block (table staged once)

// tbl layout, CLASS-major (float4 units):
//   tbl4[(c*NK + k)*8 + seg]     = m2wc = -2 * w2 * center
//   tbl4[(c*NK + k)*8 + seg + 4] = w2
// d2(x, class c) = a2[c] + sum_d ( (w2*x + m2wc) * x )

// ---------------- prep: tbl, a2[c], present[c]; init apmax/anmin
__global__ __launch_bounds__(128) void k_prep(const float* __restrict__ centers,
                                              const float* __restrict__ cw,
                                              const int* __restrict__ targets,
                                              float* __restrict__ tbl,
                                              float* __restrict__ a2,
                                              int* __restrict__ present,
                                              int* __restrict__ apmax,
                                              int* __restrict__ anmin) {
    int c = blockIdx.x, t = threadIdx.x;
    __shared__ float sred[2];
    __shared__ int ps[2];

    float acc = 0.f;
    for (int d = t; d < D_N; d += 128) {
        float wv = exp2f(cw[c * D_N + d]);
        float ce = centers[c * D_N + d];
        float p  = wv * ce;
        int k = d >> 4, seg = (d >> 2) & 3, e = d & 3;
        int base = ((c * NK + k) * 8 + seg) * 4 + e;
        tbl[base]      = -2.f * p;   // m2wc
        tbl[base + 16] = wv;         // w2
        acc = fmaf(p, ce, acc);
    }
    for (int m = 1; m < 64; m <<= 1) acc += __shfl_xor(acc, m, 64);

    int pr = 0;
    for (int i = t; i < B_N; i += 128) pr |= (targets[i] == c) ? 1 : 0;
    pr = __any(pr) ? 1 : 0;

    if ((t & 63) == 0) { sred[t >> 6] = acc; ps[t >> 6] = pr; }

    int idx = c * 128 + t;                 // 12800 threads cover 4096 rows
    if (idx < B_N) {
        apmax[idx] = 0;                    // all g > 0
        anmin[idx] = 0x7F800000;           // +inf
    }

    __syncthreads();
    if (t == 0) { a2[c] = sred[0] + sred[1]; present[c] = ps[0] | ps[1]; }
}

// ---------------- main: block = 5 classes x (SUBS x 64 rows); table staged ONCE.
// ALL x loads for a sub (6 k-steps x 4 rows = 24 float4) issued up-front as named
// registers -> one memory latency per sub instead of a 6-deep serial chain.
__global__ __launch_bounds__(256) void k_main(const float* __restrict__ inputs,
                                              const float* __restrict__ centers,
                                              const int* __restrict__ targets,
                                              const float* __restrict__ tbl,
                                              const float* __restrict__ a2,
                                              const int* __restrict__ present,
                                              int* __restrict__ apmax,
                                              int* __restrict__ anmin,
                                              float* __restrict__ cdmin) {
    __shared__ __align__(16) float4 tb[CT * NK * 8];     // 15360 B, live whole kernel
    __shared__ __align__(16) float4 red4[4 * CT * 16];   // 5120 B
    __shared__ float gbuf[CT * RT];                      // 1280 B

    int tid  = threadIdx.x;
    int w    = tid >> 6;
    int l    = tid & 63;
    int slot = l & 15;
    int seg  = l >> 4;
    int ctile = blockIdx.x;
    int c0 = ctile * CT;

    // ---- stage class slice once: CT*NK*8 = 960 float4s, contiguous in global
    {
        const float4* gsrc = (const float4*)tbl + (size_t)c0 * NK * 8;
        for (int q = tid; q < CT * NK * 8; q += 256) tb[q] = gsrc[q];
    }
    __syncthreads();

#pragma unroll 1
    for (int sub = 0; sub < SUBS; sub++) {
        int rowtile = blockIdx.y * SUBS + sub;
        bool isc = (rowtile >= NRT);

        // ---- per-thread row pointers (4 rows: slot + 16*rr)
        const float *xp0, *xp1, *xp2, *xp3;
        if (!isc) {
            const float* base = inputs + (size_t)(rowtile * RT + slot) * D_N + seg * 4;
            xp0 = base;
            xp1 = base + 16 * D_N;
            xp2 = base + 32 * D_N;
            xp3 = base + 48 * D_N;
        } else {
            int cb = (rowtile - NRT) * RT + slot;
            int r0 = min(cb,      C_N - 1);
            int r1 = min(cb + 16, C_N - 1);
            int r2 = min(cb + 32, C_N - 1);
            int r3 = min(cb + 48, C_N - 1);
            xp0 = centers + (size_t)r0 * D_N + seg * 4;
            xp1 = centers + (size_t)r1 * D_N + seg * 4;
            xp2 = centers + (size_t)r2 * D_N + seg * 4;
            xp3 = centers + (size_t)r3 * D_N + seg * 4;
        }

        int k0 = w * KW;

        // ---- issue ALL 24 x loads up-front (deep MLP, one latency per sub)
#define LOADK(KK)                                                      \
        float4 xA##KK = *(const float4*)(xp0 + (k0 + KK) * 16);        \
        float4 xB##KK = *(const float4*)(xp1 + (k0 + KK) * 16);        \
        float4 xC##KK = *(const float4*)(xp2 + (k0 + KK) * 16);        \
        float4 xD##KK = *(const float4*)(xp3 + (k0 + KK) * 16);
        LOADK(0) LOADK(1) LOADK(2) LOADK(3) LOADK(4) LOADK(5)
#undef LOADK

        float u[4][CT];
#pragma unroll
        for (int rr = 0; rr < 4; rr++)
#pragma unroll
            for (int j = 0; j < CT; j++) u[rr][j] = 0.f;

        // ---- k-loop: registers + LDS only
#define STEP(KK)                                                                   \
        {                                                                          \
            const float4* tk = tb + (k0 + KK) * 8 + seg;                           \
            _Pragma("unroll")                                                      \
            for (int j = 0; j < CT; j++) {                                         \
                float4 m2 = tk[j * (NK * 8)];                                      \
                float4 wv = tk[j * (NK * 8) + 4];                                  \
                float t;                                                           \
                t = fmaf(wv.x, xA##KK.x, m2.x); u[0][j] = fmaf(t, xA##KK.x, u[0][j]); \
                t = fmaf(wv.y, xA##KK.y, m2.y); u[0][j] = fmaf(t, xA##KK.y, u[0][j]); \
                t = fmaf(wv.z, xA##KK.z, m2.z); u[0][j] = fmaf(t, xA##KK.z, u[0][j]); \
                t = fmaf(wv.w, xA##KK.w, m2.w); u[0][j] = fmaf(t, xA##KK.w, u[0][j]); \
                t = fmaf(wv.x, xB##KK.x, m2.x); u[1][j] = fmaf(t, xB##KK.x, u[1][j]); \
                t = fmaf(wv.y, xB##KK.y, m2.y); u[1][j] = fmaf(t, xB##KK.y, u[1][j]); \
                t = fmaf(wv.z, xB##KK.z, m2.z); u[1][j] = fmaf(t, xB##KK.z, u[1][j]); \
                t = fmaf(wv.w, xB##KK.w, m2.w); u[1][j] = fmaf(t, xB##KK.w, u[1][j]); \
                t = fmaf(wv.x, xC##KK.x, m2.x); u[2][j] = fmaf(t, xC##KK.x, u[2][j]); \
                t = fmaf(wv.y, xC##KK.y, m2.y); u[2][j] = fmaf(t, xC##KK.y, u[2][j]); \
                t = fmaf(wv.z, xC##KK.z, m2.z); u[2][j] = fmaf(t, xC##KK.z, u[2][j]); \
                t = fmaf(wv.w, xC##KK.w, m2.w); u[2][j] = fmaf(t, xC##KK.w, u[2][j]); \
                t = fmaf(wv.x, xD##KK.x, m2.x); u[3][j] = fmaf(t, xD##KK.x, u[3][j]); \
                t = fmaf(wv.y, xD##KK.y, m2.y); u[3][j] = fmaf(t, xD##KK.y, u[3][j]); \
                t = fmaf(wv.z, xD##KK.z, m2.z); u[3][j] = fmaf(t, xD##KK.z, u[3][j]); \
                t = fmaf(wv.w, xD##KK.w, m2.w); u[3][j] = fmaf(t, xD##KK.w, u[3][j]); \
            }                                                                      \
        }
        STEP(0) STEP(1) STEP(2) STEP(3) STEP(4) STEP(5)
#undef STEP

        // ---- seg-reduce within wave (16-lane groups share (slot,rr))
#pragma unroll
        for (int rr = 0; rr < 4; rr++)
#pragma unroll
            for (int j = 0; j < CT; j++) {
                float a = u[rr][j];
                a += __shfl_xor(a, 16, 64);
                a += __shfl_xor(a, 32, 64);
                u[rr][j] = a;
            }

        // ---- cross-wave reduce via dedicated LDS (tb stays live)
        __syncthreads();   // prev sub's gbuf readers done; red4 safe to overwrite
        if (l < 16) {
#pragma unroll
            for (int j = 0; j < CT; j++)
                red4[(w * CT + j) * 16 + slot] =
                    make_float4(u[0][j], u[1][j], u[2][j], u[3][j]);
        }
        __syncthreads();

        // combine 4 wave-partials -> g for 320 (class,row) pairs
        const float* red = (const float*)red4;
#pragma unroll
        for (int part = 0; part < 2; part++) {
            int p = tid + part * 256;
            if (p < CT * RT) {
                int j = p >> 6, r = p & 63;
                int rr = r >> 4, sl = r & 15;
                int idx = (j * 16 + sl) * 4 + rr;
                float s = (red[(0 * CT * 16) * 4 + idx] + red[(1 * CT * 16) * 4 + idx])
                        + (red[(2 * CT * 16) * 4 + idx] + red[(3 * CT * 16) * 4 + idx]);
                gbuf[j * RT + r] = sqrtf(fmaxf(a2[c0 + j] + s, EPSF));
            }
        }
        __syncthreads();

        if (!isc) {
            // per-row ap/an -> atomics (int cmp == float cmp for g > 0;
            // min/max order-independent -> deterministic)
            if (tid < RT) {
                int row = rowtile * RT + tid;
                int ti  = targets[row];
                float ap = -1.f, an = INFINITY;
#pragma unroll
                for (int j = 0; j < CT; j++) {
                    int c = c0 + j;
                    float g = gbuf[j * RT + tid];
                    if (c == ti) ap = g;
                    else if (present[c]) an = fminf(an, g);
                }
                if (ap > 0.f) atomicMax(&apmax[row], __float_as_int(ap));
                atomicMin(&anmin[row], __float_as_int(an));
            }
        } else {
            // centers_dist partial: per class i = c0+jj, min over this sub's rows
            int jj = tid >> 4, sl = tid & 15;
            int rbase = (rowtile - NRT) * RT;     // 0 or 64
            if (jj < CT) {
                float m = INFINITY;
#pragma unroll
                for (int q = 0; q < 4; q++) {
                    int r  = sl + 16 * q;
                    int jg = rbase + r;
                    float g = gbuf[jj * RT + r];
                    if (jg < C_N && jg != c0 + jj) m = fminf(m, g);
                }
                m = fminf(m, __shfl_xor(m, 1, 64));
                m = fminf(m, __shfl_xor(m, 2, 64));
                m = fminf(m, __shfl_xor(m, 4, 64));
                m = fminf(m, __shfl_xor(m, 8, 64));
                if (sl == 0) cdmin[(c0 + jj) * 2 + (rbase >> 6)] = m;
            }
        }
    }
}

// ---------------- final: fold cdmin -> cdist, per-row loss from apmax/anmin, sum
__global__ __launch_bounds__(1024) void k_final(const int* __restrict__ apmax,
                                                const int* __restrict__ anmin,
                                                const float* __restrict__ cdmin,
                                                const int* __restrict__ targets,
                                                float* __restrict__ out) {
    int tid = threadIdx.x;
    __shared__ float cd_s[C_N];
    if (tid < C_N) cd_s[tid] = fminf(cdmin[tid * 2], cdmin[tid * 2 + 1]);
    __syncthreads();

    float sum = 0.f;
    for (int row = tid; row < B_N; row += 1024) {
        float ap = __int_as_float(apmax[row]);
        float an = __int_as_float(anmin[row]);
        float cc = cd_s[targets[row]];
        sum += (an >= cc) ? ap : (ap - an + cc);
    }
    for (int m = 1; m < 64; m <<= 1) sum += __shfl_xor(sum, m, 64);
    __shared__ float sw[16];
    if ((tid & 63) == 0) sw[tid >> 6] = sum;
    __syncthreads();
    if (tid < 64) {
        float v = (tid < 16) ? sw[tid] : 0.f;
        for (int m = 1; m < 16; m <<= 1) v += __shfl_xor(v, m, 64);
        if (tid == 0) out[0] = v / (float)B_N;
    }
}

extern "C" void kernel_launch(void* const* d_in, const int* in_sizes, int n_in,
                              void* d_out, int out_size, void* d_ws, size_t ws_size,
                              hipStream_t stream) {
    const float* inputs  = (const float*)d_in[0];
    const float* centers = (const float*)d_in[1];
    const float* cw      = (const float*)d_in[2];
    const int*   targets = (const int*)d_in[3];
    (void)in_sizes; (void)n_in; (void)out_size; (void)ws_size;

    char* ws = (char*)d_ws;
    float* tbl     = (float*)(ws + 0);         // 307200 B
    int*   apmax   = (int*)  (ws + 307200);    // 16384 B
    int*   anmin   = (int*)  (ws + 323584);    // 16384 B
    float* a2      = (float*)(ws + 339968);    // 512 B
    int*   present = (int*)  (ws + 340480);    // 512 B
    float* cdmin   = (float*)(ws + 340992);    // 800 B

    k_prep<<<C_N, 128, 0, stream>>>(centers, cw, targets, tbl, a2, present,
                                    apmax, anmin);
    dim3 grid(NT, (NRT + 2) / SUBS);   // 20 x 33 = 660 blocks
    k_main<<<grid, 256, 0, stream>>>(inputs, centers, targets, tbl, a2, present,
                                     apmax, anmin, cdmin);
    k_final<<<1, 1024, 0, stream>>>(apmax, anmin, cdmin, targets, (float*)d_out);
}

// Round 20
// 27.044 us; speedup vs baseline: 1.5057x; 1.5057x over previous
//
#include <hip/hip_runtime.h>
#include <math.h>

#define B_N 4096
#define C_N 100
#define CPAD 112
#define D_N 384
#define EPSF 1e-12f
#define NTILES 7          // class tiles of 16 (112 padded)
#define NKT 12            // ktiles per K-half (384/32)
#define RT 64             // rows per block
#define NRT (B_N / RT)    // 64 input rowtiles; rowtiles 64,65 are center rows

typedef __attribute__((ext_vector_type(8))) short short8;
typedef __attribute__((ext_vector_type(4))) float f32x4;

static __device__ __forceinline__ short f2bf(float f) {
    unsigned u = __float_as_uint(f);
    u = (u + 0x7FFFu + ((u >> 16) & 1u)) >> 16;
    return (short)u;
}

// B matrix [K=768][CPAD]: rows 0..383 = w2 (multiplies x^2), rows 384..767 = -2*w2*ctr
// (multiplies x). Stored pre-swizzled in MFMA B-fragment order:
//   bfrag[((nt*24 + kt)*4 + lg)*16 + col][e] , lane l = (lg = l>>4, col = l&15)
// ---------------- prep: bfrag (bf16), a2[c], present[c]; init apmax/anmin
__global__ __launch_bounds__(128) void k_prep(const float* __restrict__ centers,
                                              const float* __restrict__ cw,
                                              const int* __restrict__ targets,
                                              ushort* __restrict__ bfrag,
                                              float* __restrict__ a2,
                                              int* __restrict__ present,
                                              int* __restrict__ apmax,
                                              int* __restrict__ anmin) {
    int c = blockIdx.x, t = threadIdx.x;   // c in [0, 112)
    int nt = c >> 4, col = c & 15;
    __shared__ float sred[2];
    __shared__ int ps[2];

    float acc = 0.f;
    if (c < C_N) {
        for (int k = t; k < 768; k += 128) {
            int d = (k < 384) ? k : k - 384;
            float wv = exp2f(cw[c * D_N + d]);
            float ce = centers[c * D_N + d];
            float val;
            if (k < 384) { val = wv; acc = fmaf(wv * ce, ce, acc); }
            else         { val = -2.f * wv * ce; }
            int kt = k >> 5, kr = k & 31, lg = kr >> 3, e = kr & 7;
            bfrag[(((nt * 24 + kt) * 4 + lg) * 16 + col) * 8 + e] = (ushort)f2bf(val);
        }
    } else {
        for (int k = t; k < 768; k += 128) {
            int kt = k >> 5, kr = k & 31, lg = kr >> 3, e = kr & 7;
            bfrag[(((nt * 24 + kt) * 4 + lg) * 16 + col) * 8 + e] = 0;
        }
    }
    for (int m = 1; m < 64; m <<= 1) acc += __shfl_xor(acc, m, 64);

    int pr = 0;
    if (c < C_N)
        for (int i = t; i < B_N; i += 128) pr |= (targets[i] == c) ? 1 : 0;
    pr = __any(pr) ? 1 : 0;

    if ((t & 63) == 0) { sred[t >> 6] = acc; ps[t >> 6] = pr; }

    int idx = c * 128 + t;                 // 112*128 = 14336 covers 4096 rows
    if (idx < B_N) {
        apmax[idx] = 0;                    // all g > 0
        anmin[idx] = 0x7F800000;           // +inf
    }

    __syncthreads();
    if (t == 0) {
        a2[c] = (c < C_N) ? (sred[0] + sred[1]) : 0.f;
        present[c] = (c < C_N) ? (ps[0] | ps[1]) : 0;
    }
}

// ---------------- main: MFMA GEMM. block = 64 rows x 16 classes, 4 waves.
// wave w: rows [rt*64 + w*16, +16), all K=768 -> 24 x mfma_f32_16x16x32_bf16.
// A built in-register from x (x^2 for K-half 0, x for K-half 1). B from LDS frags.
// rowtile < NRT: input rows -> per-row atomic ap/an. rowtile >= NRT: center rows
// (clamped pad) -> per-class min over rows -> cdmin (direct store, unique writer).
__global__ __launch_bounds__(256) void k_main(const float* __restrict__ inputs,
                                              const float* __restrict__ centers,
                                              const int* __restrict__ targets,
                                              const ushort* __restrict__ bfrag,
                                              const float* __restrict__ a2g,
                                              const int* __restrict__ present,
                                              int* __restrict__ apmax,
                                              int* __restrict__ anmin,
                                              float* __restrict__ cdmin) {
    __shared__ __align__(16) ushort Bs[24 * 4 * 16 * 8];   // 24576 B
    __shared__ int ts[RT];
    __shared__ float cdw[4][16];

    int tid = threadIdx.x;
    int w   = tid >> 6;
    int l   = tid & 63;
    int nt  = blockIdx.x;
    int rt  = blockIdx.y;
    int c0  = nt * 16;
    bool isc = (rt >= NRT);

    // ---- stage B ntile slice (contiguous, coalesced): 1536 float4
    {
        const float4* src = (const float4*)(bfrag + (size_t)nt * (24 * 4 * 16 * 8));
        float4* dst = (float4*)Bs;
        for (int q = tid; q < 1536; q += 256) dst[q] = src[q];
    }
    if (!isc && tid < RT) ts[tid] = targets[rt * RT + tid];
    __syncthreads();

    // ---- A source pointer: lane provides A[row = l&15][k = (l>>4)*8 + e]
    int arow = w * 16 + (l & 15);
    const float* xbase;
    if (!isc) {
        xbase = inputs + (size_t)(rt * RT + arow) * D_N + ((l >> 4) * 8);
    } else {
        int cr = min((rt - NRT) * RT + arow, C_N - 1);
        xbase = centers + (size_t)cr * D_N + ((l >> 4) * 8);
    }

    f32x4 acc = {0.f, 0.f, 0.f, 0.f};
    const short8* bs8 = (const short8*)Bs;
    int lgcol = (l >> 4) * 16 + (l & 15);   // frag slot within a ktile

#pragma unroll 4
    for (int kt = 0; kt < NKT; kt++) {
        float4 v0 = *(const float4*)(xbase + kt * 32);
        float4 v1 = *(const float4*)(xbase + kt * 32 + 4);
        short8 ax, ax2;
        ax[0] = f2bf(v0.x); ax[1] = f2bf(v0.y); ax[2] = f2bf(v0.z); ax[3] = f2bf(v0.w);
        ax[4] = f2bf(v1.x); ax[5] = f2bf(v1.y); ax[6] = f2bf(v1.z); ax[7] = f2bf(v1.w);
        ax2[0] = f2bf(v0.x * v0.x); ax2[1] = f2bf(v0.y * v0.y);
        ax2[2] = f2bf(v0.z * v0.z); ax2[3] = f2bf(v0.w * v0.w);
        ax2[4] = f2bf(v1.x * v1.x); ax2[5] = f2bf(v1.y * v1.y);
        ax2[6] = f2bf(v1.z * v1.z); ax2[7] = f2bf(v1.w * v1.w);
        short8 b1 = bs8[kt * 64 + lgcol];          // w2 half
        short8 b2 = bs8[(NKT + kt) * 64 + lgcol];  // m2wc half
        acc = __builtin_amdgcn_mfma_f32_16x16x32_bf16(ax2, b1, acc, 0, 0, 0);
        acc = __builtin_amdgcn_mfma_f32_16x16x32_bf16(ax,  b2, acc, 0, 0, 0);
    }

    // ---- epilogue: D lane l = row (l>>4)*4 + r (within wave's 16), col l&15
    int c = c0 + (l & 15);
    float a2v = a2g[c];
    int prs = present[c];

    if (!isc) {
#pragma unroll
        for (int r = 0; r < 4; r++) {
            float g = sqrtf(fmaxf(a2v + acc[r], EPSF));
            int rw = w * 16 + (l >> 4) * 4 + r;
            int ti = ts[rw];
            float ap = (c == ti) ? g : -1.f;
            float an = (prs && c != ti) ? g : INFINITY;
#pragma unroll
            for (int m = 1; m < 16; m <<= 1) {
                ap = fmaxf(ap, __shfl_xor(ap, m, 64));
                an = fminf(an, __shfl_xor(an, m, 64));
            }
            if ((l & 15) == 0) {
                int row = rt * RT + rw;
                if (ap > 0.f) atomicMax(&apmax[row], __float_as_int(ap));
                atomicMin(&anmin[row], __float_as_int(an));
            }
        }
    } else {
        int h = rt - NRT;    // 0 or 1
        float m = INFINITY;
#pragma unroll
        for (int r = 0; r < 4; r++) {
            float g = sqrtf(fmaxf(a2v + acc[r], EPSF));
            int jg = h * RT + w * 16 + (l >> 4) * 4 + r;
            if (jg < C_N && jg != c) m = fminf(m, g);
        }
        m = fminf(m, __shfl_xor(m, 16, 64));
        m = fminf(m, __shfl_xor(m, 32, 64));
        if (l < 16) cdw[w][l] = m;          // col = l
        __syncthreads();                    // block-uniform branch (isc)
        if (tid < 16) {
            float mm = fminf(fminf(cdw[0][tid], cdw[1][tid]),
                             fminf(cdw[2][tid], cdw[3][tid]));
            if (c0 + tid < C_N) cdmin[(c0 + tid) * 2 + h] = mm;
        }
    }
}

// ---------------- final: fold cdmin -> cdist, per-row loss from apmax/anmin, sum
__global__ __launch_bounds__(1024) void k_final(const int* __restrict__ apmax,
                                                const int* __restrict__ anmin,
                                                const float* __restrict__ cdmin,
                                                const int* __restrict__ targets,
                                                float* __restrict__ out) {
    int tid = threadIdx.x;
    __shared__ float cd_s[C_N];
    if (tid < C_N) cd_s[tid] = fminf(cdmin[tid * 2], cdmin[tid * 2 + 1]);
    __syncthreads();

    float sum = 0.f;
    for (int row = tid; row < B_N; row += 1024) {
        float ap = __int_as_float(apmax[row]);
        float an = __int_as_float(anmin[row]);
        float cc = cd_s[targets[row]];
        sum += (an >= cc) ? ap : (ap - an + cc);
    }
    for (int m = 1; m < 64; m <<= 1) sum += __shfl_xor(sum, m, 64);
    __shared__ float sw[16];
    if ((tid & 63) == 0) sw[tid >> 6] = sum;
    __syncthreads();
    if (tid < 64) {
        float v = (tid < 16) ? sw[tid] : 0.f;
        for (int m = 1; m < 16; m <<= 1) v += __shfl_xor(v, m, 64);
        if (tid == 0) out[0] = v / (float)B_N;
    }
}

extern "C" void kernel_launch(void* const* d_in, const int* in_sizes, int n_in,
                              void* d_out, int out_size, void* d_ws, size_t ws_size,
                              hipStream_t stream) {
    const float* inputs  = (const float*)d_in[0];
    const float* centers = (const float*)d_in[1];
    const float* cw      = (const float*)d_in[2];
    const int*   targets = (const int*)d_in[3];
    (void)in_sizes; (void)n_in; (void)out_size; (void)ws_size;

    char* ws = (char*)d_ws;
    ushort* bfrag   = (ushort*)(ws + 0);       // 7*24*64*8*2 = 172032 B
    int*    apmax   = (int*)  (ws + 172032);   // 16384 B
    int*    anmin   = (int*)  (ws + 188416);   // 16384 B
    float*  a2      = (float*)(ws + 204800);   // 448 B
    int*    present = (int*)  (ws + 205312);   // 448 B
    float*  cdmin   = (float*)(ws + 205824);   // 800 B

    k_prep<<<CPAD, 128, 0, stream>>>(centers, cw, targets, bfrag, a2, present,
                                     apmax, anmin);
    dim3 grid(NTILES, NRT + 2);   // 7 x 66 = 462 blocks
    k_main<<<grid, 256, 0, stream>>>(inputs, centers, targets, bfrag, a2, present,
                                     apmax, anmin, cdmin);
    k_final<<<1, 1024, 0, stream>>>(apmax, anmin, cdmin, targets, (float*)d_out);
}

// Round 21
// 26.615 us; speedup vs baseline: 1.5300x; 1.0161x over previous
//
#include <hip/hip_runtime.h>
#include <math.h>

#define B_N 4096
#define C_N 100
#define CPAD 112
#define D_N 384
#define EPSF 1e-12f
#define NTILES 7          // class tiles of 16 (112 padded)
#define NKT24 24          // K=768 -> 24 ktiles of 32
#define RT 64             // rows per block
#define NRT (B_N / RT)    // 64 input rowtiles; rowtiles 64,65 are center rows
#define NGRP 264          // 256 input row-groups of 16 + 8 center groups

typedef __attribute__((ext_vector_type(8))) short short8;
typedef __attribute__((ext_vector_type(4))) float f32x4;

static __device__ __forceinline__ short f2bf(float f) {
    unsigned u = __float_as_uint(f);
    u = (u + 0x7FFFu + ((u >> 16) & 1u)) >> 16;
    return (short)u;
}

// Fragment layouts (HW-verified in r20): lane l, elem e of a 16x16x32 frag holds
//   A[row = l&15][k = (l>>4)*8 + e]   /   B[k = (l>>4)*8 + e][col = l&15]
// A matrix [4224 rows][K=768]: k<384 -> x[d]^2 ; k>=384 -> x[d-384]
// B matrix [K=768][CPAD]:      k<384 -> w2[c][d]; k>=384 -> -2*w2[c][d]*ctr[c][d]
// afrag[((g*24 + kt)*4 + lg)*16 + row][e] ; bfrag[((nt*24 + kt)*4 + lg)*16 + col][e]

// ---------------- prep: bid<112 -> B-frags + a2 + present + init; else A-frags
__global__ __launch_bounds__(256) void k_prep(const float* __restrict__ inputs,
                                              const float* __restrict__ centers,
                                              const float* __restrict__ cw,
                                              const int* __restrict__ targets,
                                              ushort* __restrict__ bfrag,
                                              ushort* __restrict__ afrag,
                                              float* __restrict__ a2,
                                              int* __restrict__ present,
                                              int* __restrict__ apmax,
                                              int* __restrict__ anmin,
                                              int* __restrict__ cdminI) {
    int bid = blockIdx.x, t = threadIdx.x;

    if (bid < CPAD) {
        int c = bid;
        int nt = c >> 4, col = c & 15;
        __shared__ float sred[4];
        __shared__ int ps[4];

        float acc = 0.f;
        if (c < C_N) {
#pragma unroll
            for (int it = 0; it < 3; it++) {
                int k = t + it * 256;
                int d = (k < 384) ? k : k - 384;
                float wv = exp2f(cw[c * D_N + d]);
                float ce = centers[c * D_N + d];
                float val;
                if (k < 384) { val = wv; acc = fmaf(wv * ce, ce, acc); }
                else         { val = -2.f * wv * ce; }
                int kt = k >> 5, kr = k & 31, lg = kr >> 3, e = kr & 7;
                bfrag[(((nt * 24 + kt) * 4 + lg) * 16 + col) * 8 + e] = (ushort)f2bf(val);
            }
        } else {
#pragma unroll
            for (int it = 0; it < 3; it++) {
                int k = t + it * 256;
                int kt = k >> 5, kr = k & 31, lg = kr >> 3, e = kr & 7;
                bfrag[(((nt * 24 + kt) * 4 + lg) * 16 + col) * 8 + e] = 0;
            }
        }
        for (int m = 1; m < 64; m <<= 1) acc += __shfl_xor(acc, m, 64);

        int pr = 0;
        if (c < C_N)
            for (int i = t; i < B_N; i += 256) pr |= (targets[i] == c) ? 1 : 0;
        pr = __any(pr) ? 1 : 0;

        if ((t & 63) == 0) { sred[t >> 6] = acc; ps[t >> 6] = pr; }

        int idx = bid * 256 + t;               // 28672 covers 4096
        if (idx < B_N) {
            apmax[idx] = 0;                    // all g > 0
            anmin[idx] = 0x7F800000;           // +inf
        }
        if (bid == 0 && t < CPAD) cdminI[t] = 0x7F800000;

        __syncthreads();
        if (t == 0) {
            a2[c] = (c < C_N) ? ((sred[0] + sred[1]) + (sred[2] + sred[3])) : 0.f;
            present[c] = (c < C_N) ? (ps[0] | ps[1] | ps[2] | ps[3]) : 0;
        }
    } else {
        // ---- A-fragment build for row-group g (16 rows x K=768)
        int g = bid - CPAD;                    // 0..263
#pragma unroll
        for (int it = 0; it < 6; it++) {
            int cid = t + it * 256;            // 0..1535
            int row = cid & 15;
            int kc  = cid >> 4;                // 8-k chunk, 0..95
            const float* src;
            if (g < 256) {
                src = inputs + (size_t)(g * 16 + row) * D_N;
            } else {
                int cr = min((g - 256) * 16 + row, C_N - 1);
                src = centers + (size_t)cr * D_N;
            }
            int d0 = (kc < 48) ? kc * 8 : (kc - 48) * 8;
            float4 v0 = *(const float4*)(src + d0);
            float4 v1 = *(const float4*)(src + d0 + 4);
            short8 o;
            if (kc < 48) {
                o[0] = f2bf(v0.x * v0.x); o[1] = f2bf(v0.y * v0.y);
                o[2] = f2bf(v0.z * v0.z); o[3] = f2bf(v0.w * v0.w);
                o[4] = f2bf(v1.x * v1.x); o[5] = f2bf(v1.y * v1.y);
                o[6] = f2bf(v1.z * v1.z); o[7] = f2bf(v1.w * v1.w);
            } else {
                o[0] = f2bf(v0.x); o[1] = f2bf(v0.y);
                o[2] = f2bf(v0.z); o[3] = f2bf(v0.w);
                o[4] = f2bf(v1.x); o[5] = f2bf(v1.y);
                o[6] = f2bf(v1.z); o[7] = f2bf(v1.w);
            }
            int kt = kc >> 2, lg = kc & 3;
            *(short8*)(afrag + (size_t)(((g * 24 + kt) * 4 + lg) * 16 + row) * 8) = o;
        }
    }
}

// ---------------- main: pure fragment GEMM, no LDS, no barriers.
// block = 64 rows x 16 classes, 4 waves; wave w: row-group g, 24 MFMA over K=768.
__global__ __launch_bounds__(256) void k_main(const ushort* __restrict__ afrag,
                                              const ushort* __restrict__ bfrag,
                                              const int* __restrict__ targets,
                                              const float* __restrict__ a2g,
                                              const int* __restrict__ present,
                                              int* __restrict__ apmax,
                                              int* __restrict__ anmin,
                                              int* __restrict__ cdminI) {
    int tid = threadIdx.x;
    int w   = tid >> 6;
    int l   = tid & 63;
    int nt  = blockIdx.x;
    int rt  = blockIdx.y;
    int c0  = nt * 16;
    bool isc = (rt >= NRT);

    int g = isc ? (256 + (rt - NRT) * 4 + w) : (rt * 4 + w);
    int slot = (l >> 4) * 16 + (l & 15);

    const short8* A = (const short8*)afrag + (size_t)g * 24 * 64;
    const short8* B = (const short8*)bfrag + (size_t)nt * 24 * 64;

    f32x4 acc0 = {0.f, 0.f, 0.f, 0.f};
    f32x4 acc1 = {0.f, 0.f, 0.f, 0.f};
#pragma unroll 6
    for (int kt = 0; kt < NKT24; kt++) {
        short8 a = A[kt * 64 + slot];
        short8 b = B[kt * 64 + slot];
        if (kt & 1) acc1 = __builtin_amdgcn_mfma_f32_16x16x32_bf16(a, b, acc1, 0, 0, 0);
        else        acc0 = __builtin_amdgcn_mfma_f32_16x16x32_bf16(a, b, acc0, 0, 0, 0);
    }
    f32x4 acc = acc0 + acc1;

    // ---- epilogue: D lane l = row (l>>4)*4 + r (within wave's 16), col l&15
    int c = c0 + (l & 15);
    float a2v = a2g[c];
    int prs = present[c];

    if (!isc) {
#pragma unroll
        for (int r = 0; r < 4; r++) {
            float gv = sqrtf(fmaxf(a2v + acc[r], EPSF));
            int rw  = w * 16 + (l >> 4) * 4 + r;
            int row = rt * RT + rw;
            int ti  = targets[row];               // 16-lane broadcast read
            float ap = (c == ti) ? gv : -1.f;
            float an = (prs && c != ti) ? gv : INFINITY;
#pragma unroll
            for (int m = 1; m < 16; m <<= 1) {
                ap = fmaxf(ap, __shfl_xor(ap, m, 64));
                an = fminf(an, __shfl_xor(an, m, 64));
            }
            if ((l & 15) == 0) {
                if (ap > 0.f) atomicMax(&apmax[row], __float_as_int(ap));
                atomicMin(&anmin[row], __float_as_int(an));
            }
        }
    } else {
        float m = INFINITY;
#pragma unroll
        for (int r = 0; r < 4; r++) {
            float gv = sqrtf(fmaxf(a2v + acc[r], EPSF));
            int jg = (rt - NRT) * RT + w * 16 + (l >> 4) * 4 + r;
            if (jg < C_N && jg != c) m = fminf(m, gv);
        }
        m = fminf(m, __shfl_xor(m, 16, 64));
        m = fminf(m, __shfl_xor(m, 32, 64));
        if (l < 16 && c < C_N && m < INFINITY)
            atomicMin(&cdminI[c], __float_as_int(m));
    }
}

// ---------------- final: per-row loss from apmax/anmin + cdminI, sum
__global__ __launch_bounds__(1024) void k_final(const int* __restrict__ apmax,
                                                const int* __restrict__ anmin,
                                                const int* __restrict__ cdminI,
                                                const int* __restrict__ targets,
                                                float* __restrict__ out) {
    int tid = threadIdx.x;
    __shared__ float cd_s[C_N];
    if (tid < C_N) cd_s[tid] = __int_as_float(cdminI[tid]);
    __syncthreads();

    float sum = 0.f;
    for (int row = tid; row < B_N; row += 1024) {
        float ap = __int_as_float(apmax[row]);
        float an = __int_as_float(anmin[row]);
        float cc = cd_s[targets[row]];
        sum += (an >= cc) ? ap : (ap - an + cc);
    }
    for (int m = 1; m < 64; m <<= 1) sum += __shfl_xor(sum, m, 64);
    __shared__ float sw[16];
    if ((tid & 63) == 0) sw[tid >> 6] = sum;
    __syncthreads();
    if (tid < 64) {
        float v = (tid < 16) ? sw[tid] : 0.f;
        for (int m = 1; m < 16; m <<= 1) v += __shfl_xor(v, m, 64);
        if (tid == 0) out[0] = v / (float)B_N;
    }
}

extern "C" void kernel_launch(void* const* d_in, const int* in_sizes, int n_in,
                              void* d_out, int out_size, void* d_ws, size_t ws_size,
                              hipStream_t stream) {
    const float* inputs  = (const float*)d_in[0];
    const float* centers = (const float*)d_in[1];
    const float* cw      = (const float*)d_in[2];
    const int*   targets = (const int*)d_in[3];
    (void)in_sizes; (void)n_in; (void)out_size; (void)ws_size;

    char* ws = (char*)d_ws;
    ushort* bfrag   = (ushort*)(ws + 0);        // 7*24*64*8*2   = 172032 B
    ushort* afrag   = (ushort*)(ws + 172032);   // 264*24*64*8*2 = 6488064 B
    int*    apmax   = (int*)  (ws + 6660096);   // 16384 B
    int*    anmin   = (int*)  (ws + 6676480);   // 16384 B
    float*  a2      = (float*)(ws + 6692864);   // 448 B
    int*    present = (int*)  (ws + 6693376);   // 448 B
    int*    cdminI  = (int*)  (ws + 6693888);   // 448 B

    k_prep<<<CPAD + NGRP, 256, 0, stream>>>(inputs, centers, cw, targets,
                                            bfrag, afrag, a2, present,
                                            apmax, anmin, cdminI);
    dim3 grid(NTILES, NRT + 2);   // 7 x 66 = 462 blocks
    k_main<<<grid, 256, 0, stream>>>(afrag, bfrag, targets, a2, present,
                                     apmax, anmin, cdminI);
    k_final<<<1, 1024, 0, stream>>>(apmax, anmin, cdminI, targets, (float*)d_out);
}